// Round 14
// baseline (136.459 us; speedup 1.0000x reference)
//
#include <hip/hip_runtime.h>

// SSIM loss via MFMA band-matrix convolutions (gfx950).
// R19/R21: LDS-staged tile via global_load_lds + rotation swizzle. Tile 41.6
//   -> ~37.8us (4 blocks/CU). KEY R21 finding: dur_us has a FIXED ~87.5us
//   harness overhead (2x 256MiB fillBuffer re-poison @41us inside the timed
//   region); controllable part = tile + finish only.
//   Residency alone didn't raise HBM duty: __syncthreads DRAINS vmcnt(0)
//   (m97 barrier-drain), so no load is ever in flight during compute.
// R22: intra-block pipeline, counted vmcnt + RAW s_barrier (T3/T4).
//   Block = 64x128 strip = 4 tiles, sx double-buffered:
//   STAGE(it+1) -> s_waitcnt vmcnt(7) (prev stage only; 7 newest in flight)
//   -> s_barrier -> COMPUTE(it) -> s_barrier. Scratch single-slot (5 field
//   passes, per-wave DS order makes WAR safe): LDS 56320+6144=62464B.
//   Band-table loads fenced vmcnt(0) BEFORE stage0 so counted waits see
//   only stage loads. Predict tile ~24-28us => dur_us ~112-118.
// R23 (this round): unchanged resubmit -- R22 bench infra-failed
//   (GPUAcquisitionTimeout); the pipelined kernel has not been measured.

namespace {
constexpr int IMG   = 512;
constexpr int NCH   = 48;                  // 16 * 3
constexpr int TW    = 64;                  // tile cols
constexpr int TH    = 32;                  // tile rows
constexpr int NT    = 4;                   // tiles per block (vertical strip)
constexpr int WR    = 44;                  // staged window rows (ty-5..ty+38)
constexpr int WC    = 80;                  // staged window cols (tx-8..tx+71)
constexpr int SLOTS = WC / 4;              // 20 16B-slots per row
constexpr int TSLOT = WR * SLOTS;          // 880 slots per tensor
constexpr int NSL   = 2 * TSLOT;           // 1760 slots total
constexpr int TPX   = IMG / TW;            // 8
constexpr int NSTRIP= IMG / (TH * NT);     // 4 strips of 128 rows
constexpr int NBLK  = TPX * NSTRIP * NCH;  // 1536
constexpr int NPART = NBLK * 4;            // 6144 (one f32 per wave)
constexpr int RS    = 48;                  // scratch p-stride (>=48 REQUIRED)
constexpr int SXN   = WR * WC;             // 3520 f32 per tensor

constexpr float Wf[11] = {
    0.00102838f, 0.00759876f, 0.03600077f, 0.10936069f, 0.21300554f,
    0.26601172f,
    0.21300554f, 0.10936069f, 0.03600077f, 0.00759876f, 0.00102838f };

constexpr float band_wc(int d) {           // W[d] for d in [0,11), else 0
    return (d >= 0 && d < 11) ? Wf[d] : 0.f;
}

// constexpr f32 -> f16 bits, round-to-nearest-even (matches runtime cast).
constexpr unsigned short f2h(float f) {
    if (f == 0.f) return 0;
    unsigned u = __builtin_bit_cast(unsigned, f);
    int  he = int((u >> 23) & 0xff) - 127 + 15;
    unsigned hm   = (u & 0x7fffff) >> 13;
    unsigned rest = u & 0x1fff;
    if (rest > 0x1000 || (rest == 0x1000 && (hm & 1))) ++hm;
    return (unsigned short)((unsigned(he) << 10) + hm);
}

struct Tabs { unsigned short a[64][8]; unsigned short b[64][8]; };
constexpr Tabs build_tabs() {
    Tabs t{};
    for (int lane = 0; lane < 64; ++lane) {
        const int nr = lane & 15, quad = lane >> 4;
        for (int jj = 0; jj < 8; ++jj) {
            const int k = quad * 8 + jj;
            t.a[lane][jj] = f2h(band_wc(k - nr));       // V-pass A: W[k-m]
            t.b[lane][jj] = f2h(band_wc(k - nr - 3));   // H-pass B: W[k-n-3]
        }
    }
    return t;
}
}

__device__ __constant__ __align__(16) Tabs g_tabs = build_tabs();

typedef _Float16 half8 __attribute__((ext_vector_type(8)));
typedef _Float16 half4v __attribute__((ext_vector_type(4)));
typedef _Float16 h2 __attribute__((ext_vector_type(2)));
typedef float float4v __attribute__((ext_vector_type(4)));
typedef float float2v __attribute__((ext_vector_type(2)));

__device__ inline h2 pk(float a, float b) {
    auto v = __builtin_amdgcn_cvt_pkrtz(a, b);
    h2 r;
    __builtin_memcpy(&r, &v, sizeof(r));
    return r;
}

union H8 { half8 v; h2 p[4]; };

// async global -> LDS, 16B per lane; dest = wave-uniform base + lane*16.
__device__ __forceinline__ void gl2l(const float* g, void* l) {
    __builtin_amdgcn_global_load_lds(
        (const __attribute__((address_space(1))) unsigned int*)g,
        (__attribute__((address_space(3))) unsigned int*)l, 16, 0, 0);
}

__global__ __launch_bounds__(256, 2) void ssim_tile_kernel(
    const float* __restrict__ pred, const float* __restrict__ tgt,
    float* __restrict__ partial)
{
    // double-buffered staged window, rotation-swizzled slots:
    //   LDS[buf][tens][row][pos] = global slot (pos - row&7) mod 20
    __shared__ __align__(16) float sx[2][2 * SXN];           // 56320 B
    // wave-private transpose scratch [wave][x][p], single slot
    __shared__ __align__(16) _Float16 sc[4][16][RS];         // 6144 B

    const int t    = threadIdx.x;
    const int w    = t >> 6;
    const int lane = t & 63;
    const int nr   = lane & 15;
    const int quad = lane >> 4;

    const int bid  = blockIdx.x;
    const int img  = bid >> 5;             // 32 strips per plane (8 x 4)
    const int tile = bid & 31;
    const int tx   = (tile & 7) * TW;
    const int ty0  = (tile >> 3) * (TH * NT);

    const float* __restrict__ p = pred + (size_t)img * (IMG * IMG);
    const float* __restrict__ q = tgt  + (size_t)img * (IMG * IMG);

    // ---- band fragments FIRST, then full drain: the counted vmcnt waits
    //      below must see ONLY stage loads in the queue.
    const half8 Aband = *(const half8*)(g_tabs.a[lane]);
    const half8 Bband = *(const half8*)(g_tabs.b[lane]);
    asm volatile("s_waitcnt vmcnt(0)" ::: "memory");

    const float4v zf = {0.f, 0.f, 0.f, 0.f};
    const half8 z8 = {};
    constexpr float C1 = 1e-4f, C2 = 9e-4f;
    const float2v C1v = {C1, C1};
    const float2v C2v = {C2, C2};
    const float2v K12 = {C1 + C2, C1 + C2};
    float2v lsum2 = {0.f, 0.f};

    // ---- STAGE: issue 7 gload_lds per wave for tile `it` into buf ----
    auto STAGE = [&](int it, int buf) {
        const int ty = ty0 + TH * it;
        #pragma unroll
        for (int i = 0; i < 7; ++i) {
            const int j = i * 4 + w;       // wave-uniform instr index 0..27
            const int L = j * 64 + lane;
            if (L < NSL) {                 // EXEC-mask the 32-lane tail
                const int tens = (L >= TSLOT) ? 1 : 0;
                const int Lt   = L - tens * TSLOT;
                const int row  = Lt / SLOTS;
                const int sp   = Lt - row * SLOTS;
                int sl = sp - (row & 7);
                if (sl < 0) sl += SLOTS;
                const int gy   = min(max(ty - 5 + row, 0), IMG - 1);
                const int gx   = min(max(tx - 8 + 4 * sl, 0), IMG - 4);
                const float* src = (tens ? q : p) + gy * IMG + gx;
                gl2l(src, (char*)sx[buf] + (size_t)j * 1024);
            }
        }
    };

    // ---- COMPUTE: full H->transpose->V->epilogue for tile `it` ----
    auto COMPUTE = [&](int it, int buf) {
        const int ty = ty0 + TH * it;
        const int c  = w;                  // wave owns chunk c (16 out cols)
        const bool okc_ = ((unsigned)(tx + 16 * c - 8 + 8 * quad)
                           <= (unsigned)(IMG - 8));

        half8 fx[3], fy[3];
        #pragma unroll
        for (int s = 0; s < 3; ++s) {
            const int row  = 16 * s + nr;
            const int rowr = min(row, WR - 1);
            const bool ok  = okc_ && (row < WR) &&
                             ((unsigned)(ty - 5 + row) < (unsigned)IMG);
            const int sl0 = 4 * c + 2 * quad;
            const int r7  = rowr & 7;
            int pos0 = sl0 + r7;     if (pos0 >= SLOTS) pos0 -= SLOTS;
            int pos1 = sl0 + 1 + r7; if (pos1 >= SLOTS) pos1 -= SLOTS;
            const float* b0 = sx[buf] + rowr * WC;
            const float* b1 = b0 + SXN;
            float4 xA = *(const float4*)(b0 + 4 * pos0);
            float4 xB = *(const float4*)(b0 + 4 * pos1);
            float4 yA = *(const float4*)(b1 + 4 * pos0);
            float4 yB = *(const float4*)(b1 + 4 * pos1);
            H8 ax, ay;
            ax.p[0] = pk(xA.x, xA.y); ax.p[1] = pk(xA.z, xA.w);
            ax.p[2] = pk(xB.x, xB.y); ax.p[3] = pk(xB.z, xB.w);
            ay.p[0] = pk(yA.x, yA.y); ay.p[1] = pk(yA.z, yA.w);
            ay.p[2] = pk(yB.x, yB.y); ay.p[3] = pk(yB.z, yB.w);
            if (!ok) { ax.v = z8; ay.v = z8; }
            fx[s] = ax.v;
            fy[s] = ay.v;
        }

        auto hw = [&](int s, float4v d) {
            h2 lo = pk(d[0], d[1]);
            h2 hi = pk(d[2], d[3]);
            half4v hh = {lo[0], lo[1], hi[0], hi[1]};
            *(half4v*)&sc[w][nr][16 * s + 4 * quad] = hh;         // b64
        };
        auto rdv = [&](int pb) -> half8 {
            return *(const half8*)&sc[w][nr][pb + 8 * quad];      // b128
        };
        #define HMA(a) __builtin_amdgcn_mfma_f32_16x16x32_f16((a), Bband, zf, 0, 0, 0)
        #define VMA(b) __builtin_amdgcn_mfma_f32_16x16x32_f16(Aband, (b), zf, 0, 0, 0)

        // 5 sequential field passes through the single-slot scratch.
        // Per-wave in-order DS pipe: pass f's rdv reads precede pass f+1's
        // hw writes in program order -> WAR safe (same argument as R19/R21).
        float4v a0[5], a1[5];
        #pragma unroll
        for (int f = 0; f < 5; ++f) {
            #pragma unroll
            for (int s = 0; s < 3; ++s) {
                half8 prod = (f == 0) ? fx[s]
                           : (f == 1) ? fy[s]
                           : (f == 2) ? fx[s] * fx[s]
                           : (f == 3) ? fy[s] * fy[s]
                                      : fx[s] * fy[s];
                hw(s, HMA(prod));
            }
            a0[f] = VMA(rdv(0));
            a1[f] = VMA(rdv(16));
        }
        #undef HMA
        #undef VMA

        #pragma unroll
        for (int v = 0; v < 2; ++v) {
            const float4v* A = v ? a1 : a0;
            #pragma unroll
            for (int h = 0; h < 2; ++h) {
                float2v mx  = {A[0][2*h], A[0][2*h+1]};
                float2v my  = {A[1][2*h], A[1][2*h+1]};
                float2v ex2 = {A[2][2*h], A[2][2*h+1]};
                float2v ey2 = {A[3][2*h], A[3][2*h+1]};
                float2v exy = {A[4][2*h], A[4][2*h+1]};
                float2v P  = mx * my;
                float2v U  = mx * mx + my * my + C1v;
                float2v n1 = 2.f * P + C1v;
                float2v n2 = 2.f * (exy - P) + C2v;
                float2v num = n1 * n2;
                float2v e1 = (ex2 + ey2) - U + K12;
                float2v den = U * e1;
                float2v r = {__builtin_amdgcn_rcpf(den.x),
                             __builtin_amdgcn_rcpf(den.y)};
                lsum2 += num * r;
            }
        }
    };

    // ===== pipelined strip loop: stage(it+1) in flight during compute(it) ====
    STAGE(0, 0);
    #pragma unroll 1
    for (int it = 0; it < NT; ++it) {
        if (it < NT - 1) {
            STAGE(it + 1, (it + 1) & 1);
            asm volatile("s_waitcnt vmcnt(7)" ::: "memory");  // prev stage done
        } else {
            asm volatile("s_waitcnt vmcnt(0)" ::: "memory");
        }
        __builtin_amdgcn_sched_barrier(0);
        __builtin_amdgcn_s_barrier();      // raw: does NOT drain vmcnt
        COMPUTE(it, it & 1);
        __builtin_amdgcn_s_barrier();      // all waves done reading buf
    }

    float lsum = lsum2.x + lsum2.y;
    #pragma unroll
    for (int off = 32; off > 0; off >>= 1)
        lsum += __shfl_down(lsum, off, 64);
    if (lane == 0) partial[(bid << 2) + w] = lsum;
}

// Single-block finish: 1024 threads x 6 loads, deterministic tree reduce.
__global__ __launch_bounds__(1024) void ssim_finish(
    const float* __restrict__ partial, float* __restrict__ out)
{
    __shared__ float wred[16];
    const int t = threadIdx.x;
    float s = 0.f;
    #pragma unroll
    for (int i = 0; i < NPART / 1024; ++i)
        s += partial[t + i * 1024];
    #pragma unroll
    for (int off = 32; off > 0; off >>= 1)
        s += __shfl_down(s, off, 64);
    if ((t & 63) == 0) wred[t >> 6] = s;
    __syncthreads();
    if (t == 0) {
        float acc = 0.f;
        #pragma unroll
        for (int i = 0; i < 16; ++i) acc += wred[i];
        out[0] = 1.f - acc * (1.f / (float)((long long)NCH * IMG * IMG));
    }
}

extern "C" void kernel_launch(void* const* d_in, const int* in_sizes, int n_in,
                              void* d_out, int out_size, void* d_ws, size_t ws_size,
                              hipStream_t stream)
{
    const float* pred = (const float*)d_in[0];
    const float* tgt  = (const float*)d_in[1];
    float* out     = (float*)d_out;
    float* partial = (float*)d_ws;    // NPART floats = 24 KB

    ssim_tile_kernel<<<NBLK, 256, 0, stream>>>(pred, tgt, partial);
    ssim_finish<<<1, 1024, 0, stream>>>(partial, out);
}

// Round 15
// 130.338 us; speedup vs baseline: 1.0470x; 1.0470x over previous
//
#include <hip/hip_runtime.h>

// SSIM loss via MFMA band-matrix convolutions (gfx950).
// R21 (best): TW64/TH32 f32 window via gload_lds, 4 blocks/CU, tile ~37.8us.
// R22/R23: counted-vmcnt pipeline REGRESSED to 47.7us. Post-mortem:
//   (a) RS=48 scratch = 4 bank-starts (24nr mod 32, period 4) -> conflicts
//       5.6M cy (~10us/CU serialized) vs RS=56's 8 starts;
//   (b) 2 blocks/CU + single-slot scratch serialized 5 field passes ->
//       longer latency chains exactly when TLP halved;
//   (c) stage writes + compute reads contend for the ONE LDS pipe (~146KB
//       traffic/tile) -> pipeline had no slack. Lesson: cut LDS bytes+chains.
// R24 (this round): F16 WINDOW, reg-staged (T14):
//   stage once: global f32x4 x2 -> cvt_pkrtz -> ds_write_b128 (rotated slots);
//   fragment read = ONE b128, zero VALU (was 4x f32 reads + 8 cvt);
//   scratch back to R19's 2-slot ping-pong RS=56 (8 bank-starts, field-pair
//   ILP). LDS 14080+14336=28416B -> 5 blocks/CU (20 waves). Grid 6144,
//   1 tile/block, plain __syncthreads. Predict tile ~28-31us, dur ~117-121.

namespace {
constexpr int IMG   = 512;
constexpr int NCH   = 48;                  // 16 * 3
constexpr int TW    = 64;                  // tile cols
constexpr int TH    = 32;                  // tile rows
constexpr int WR    = 44;                  // staged window rows (ty-5..ty+38)
constexpr int WC    = 80;                  // staged window cols (tx-8..tx+71)
constexpr int SLOTS = WC / 8;              // 10 16B-f16-slots per row (8 cols)
constexpr int NU    = 2 * WR * SLOTS;      // 880 staging units
constexpr int TPX   = IMG / TW;            // 8
constexpr int TPY   = IMG / TH;            // 16
constexpr int NBLK  = TPX * TPY * NCH;     // 6144
constexpr int NPART = NBLK * 4;            // 24576 (one f32 per wave)
constexpr int RS    = 56;                  // scratch p-stride (f16): 112B rows,
                                           // 28nr mod 32 -> 8 bank-starts
constexpr float Wf[11] = {
    0.00102838f, 0.00759876f, 0.03600077f, 0.10936069f, 0.21300554f,
    0.26601172f,
    0.21300554f, 0.10936069f, 0.03600077f, 0.00759876f, 0.00102838f };

constexpr float band_wc(int d) {           // W[d] for d in [0,11), else 0
    return (d >= 0 && d < 11) ? Wf[d] : 0.f;
}

// constexpr f32 -> f16 bits, round-to-nearest-even (matches runtime cast).
constexpr unsigned short f2h(float f) {
    if (f == 0.f) return 0;
    unsigned u = __builtin_bit_cast(unsigned, f);
    int  he = int((u >> 23) & 0xff) - 127 + 15;
    unsigned hm   = (u & 0x7fffff) >> 13;
    unsigned rest = u & 0x1fff;
    if (rest > 0x1000 || (rest == 0x1000 && (hm & 1))) ++hm;
    return (unsigned short)((unsigned(he) << 10) + hm);
}

struct Tabs { unsigned short a[64][8]; unsigned short b[64][8]; };
constexpr Tabs build_tabs() {
    Tabs t{};
    for (int lane = 0; lane < 64; ++lane) {
        const int nr = lane & 15, quad = lane >> 4;
        for (int jj = 0; jj < 8; ++jj) {
            const int k = quad * 8 + jj;
            t.a[lane][jj] = f2h(band_wc(k - nr));       // V-pass A: W[k-m]
            t.b[lane][jj] = f2h(band_wc(k - nr - 3));   // H-pass B: W[k-n-3]
        }
    }
    return t;
}
}

__device__ __constant__ __align__(16) Tabs g_tabs = build_tabs();

typedef _Float16 half8 __attribute__((ext_vector_type(8)));
typedef _Float16 half4v __attribute__((ext_vector_type(4)));
typedef _Float16 h2 __attribute__((ext_vector_type(2)));
typedef float float4v __attribute__((ext_vector_type(4)));
typedef float float2v __attribute__((ext_vector_type(2)));

__device__ inline h2 pk(float a, float b) {
    auto v = __builtin_amdgcn_cvt_pkrtz(a, b);
    h2 r;
    __builtin_memcpy(&r, &v, sizeof(r));
    return r;
}

union H8 { half8 v; h2 p[4]; };

__global__ __launch_bounds__(256, 5) void ssim_tile_kernel(
    const float* __restrict__ pred, const float* __restrict__ tgt,
    float* __restrict__ partial)
{
    // f16 window, rotation-swizzled 16B slots:
    //   wf[tens][row][pos] holds logical slot (pos - row&7) mod 10
    __shared__ __align__(16) _Float16 wf[2][WR][SLOTS * 8];  // 14080 B
    // wave-private transpose scratch [wave][pingpong][x][p]
    __shared__ __align__(16) _Float16 sc[4][2][16][RS];      // 14336 B

    const int t    = threadIdx.x;
    const int w    = t >> 6;
    const int lane = t & 63;
    const int nr   = lane & 15;
    const int quad = lane >> 4;

    const int bid  = blockIdx.x;
    const int img  = bid >> 7;             // 128 tiles per plane (8 x 16)
    const int tile = bid & 127;
    const int tx   = (tile & 7) * TW;
    const int ty   = (tile >> 3) * TH;

    const float* __restrict__ p = pred + (size_t)img * (IMG * IMG);
    const float* __restrict__ q = tgt  + (size_t)img * (IMG * IMG);

    // ===== P1: reg-stage window as f16 (4 units/thread, masked) =====
    // unit u: tens = u>=440; v = u-440t; row = v/10; pos = v%10;
    //   stored slot sl = (pos - row&7) mod 10; cols tx-8+8sl..+7
    #pragma unroll
    for (int k = 0; k < 4; ++k) {
        const int u = t + k * 256;
        if (u < NU) {
            const int tens = (u >= NU / 2) ? 1 : 0;
            const int v    = u - tens * (NU / 2);
            const int row  = v / SLOTS;
            const int pos  = v - row * SLOTS;
            int sl = pos - (row & 7);
            if (sl < 0) sl += SLOTS;
            const int gy = min(max(ty - 5 + row, 0), IMG - 1);
            const int gx = min(max(tx - 8 + 8 * sl, 0), IMG - 8);
            const float* src = (tens ? q : p) + gy * IMG + gx;
            float4 a = *(const float4*)src;
            float4 b = *(const float4*)(src + 4);
            H8 h;
            h.p[0] = pk(a.x, a.y); h.p[1] = pk(a.z, a.w);
            h.p[2] = pk(b.x, b.y); h.p[3] = pk(b.z, b.w);
            *(half8*)&wf[tens][row][pos * 8] = h.v;
        }
    }
    __syncthreads();

    // ---- band fragments from the compile-time table ----
    const half8 Aband = *(const half8*)(g_tabs.a[lane]);
    const half8 Bband = *(const half8*)(g_tabs.b[lane]);
    const float4v zf = {0.f, 0.f, 0.f, 0.f};
    const half8 z8 = {};

    constexpr float C1 = 1e-4f, C2 = 9e-4f;
    const float2v C1v = {C1, C1};
    const float2v C2v = {C2, C2};
    const float2v K12 = {C1 + C2, C1 + C2};
    float2v lsum2 = {0.f, 0.f};

    // ===== P2: each wave owns chunk c = w (16 output cols) =====
    {
        const int c = w;
        // frag col base tx+16c-8+8quad; zero when outside [0,512)
        const bool okc_ = ((unsigned)(tx + 16 * c - 8 + 8 * quad)
                           <= (unsigned)(IMG - 8));

        // ---- read 6 A-frags (3 stripes x {x,y}): ONE b128 each ----
        half8 fx[3], fy[3];
        #pragma unroll
        for (int s = 0; s < 3; ++s) {
            const int row  = 16 * s + nr;
            const int rowr = min(row, WR - 1);
            const bool ok  = okc_ && (row < WR) &&
                             ((unsigned)(ty - 5 + row) < (unsigned)IMG);
            const int sl = 2 * c + quad;           // logical 8-col slot
            int pos = sl + (rowr & 7);
            if (pos >= SLOTS) pos -= SLOTS;
            half8 ax = *(const half8*)&wf[0][rowr][pos * 8];
            half8 ay = *(const half8*)&wf[1][rowr][pos * 8];
            if (!ok) { ax = z8; ay = z8; }
            fx[s] = ax;
            fy[s] = ay;
        }

        // ---- H-MFMA -> transposed scratch -> V-MFMA (2-slot ping-pong) ----
        auto hw = [&](int slot, int s, float4v d) {
            h2 lo = pk(d[0], d[1]);
            h2 hi = pk(d[2], d[3]);
            half4v hh = {lo[0], lo[1], hi[0], hi[1]};
            *(half4v*)&sc[w][slot][nr][16 * s + 4 * quad] = hh;   // b64
        };
        auto rdv = [&](int slot, int pb) -> half8 {
            return *(const half8*)&sc[w][slot][nr][pb + 8 * quad]; // b128
        };
        #define HMA(a) __builtin_amdgcn_mfma_f32_16x16x32_f16((a), Bband, zf, 0, 0, 0)
        #define VMA(b) __builtin_amdgcn_mfma_f32_16x16x32_f16(Aband, (b), zf, 0, 0, 0)

        float4v a0[5], a1[5];   // V accumulators: out rows ty+.., ty+16+..
        // pass 1: x, y
        #pragma unroll
        for (int s = 0; s < 3; ++s) { hw(0, s, HMA(fx[s])); hw(1, s, HMA(fy[s])); }
        a0[0] = VMA(rdv(0, 0));  a1[0] = VMA(rdv(0, 16));
        a0[1] = VMA(rdv(1, 0));  a1[1] = VMA(rdv(1, 16));
        // pass 2: x*x, y*y (same-wave DS order: reads above precede writes)
        #pragma unroll
        for (int s = 0; s < 3; ++s) { hw(0, s, HMA(fx[s] * fx[s])); hw(1, s, HMA(fy[s] * fy[s])); }
        a0[2] = VMA(rdv(0, 0));  a1[2] = VMA(rdv(0, 16));
        a0[3] = VMA(rdv(1, 0));  a1[3] = VMA(rdv(1, 16));
        // pass 3: x*y
        #pragma unroll
        for (int s = 0; s < 3; ++s) { hw(0, s, HMA(fx[s] * fy[s])); }
        a0[4] = VMA(rdv(0, 0));  a1[4] = VMA(rdv(0, 16));
        #undef HMA
        #undef VMA

        // ---- packed-f32 SSIM epilogue for both 16-row halves ----
        #pragma unroll
        for (int v = 0; v < 2; ++v) {
            const float4v* A = v ? a1 : a0;
            #pragma unroll
            for (int h = 0; h < 2; ++h) {
                float2v mx  = {A[0][2*h], A[0][2*h+1]};
                float2v my  = {A[1][2*h], A[1][2*h+1]};
                float2v ex2 = {A[2][2*h], A[2][2*h+1]};
                float2v ey2 = {A[3][2*h], A[3][2*h+1]};
                float2v exy = {A[4][2*h], A[4][2*h+1]};
                float2v P  = mx * my;
                float2v U  = mx * mx + my * my + C1v;
                float2v n1 = 2.f * P + C1v;
                float2v n2 = 2.f * (exy - P) + C2v;
                float2v num = n1 * n2;
                float2v e1 = (ex2 + ey2) - U + K12;
                float2v den = U * e1;
                float2v r = {__builtin_amdgcn_rcpf(den.x),
                             __builtin_amdgcn_rcpf(den.y)};
                lsum2 += num * r;
            }
        }
    }

    float lsum = lsum2.x + lsum2.y;
    #pragma unroll
    for (int off = 32; off > 0; off >>= 1)
        lsum += __shfl_down(lsum, off, 64);
    if (lane == 0) partial[(bid << 2) + w] = lsum;
}

// Single-block finish: 1024 threads x 24 loads, deterministic tree reduce.
__global__ __launch_bounds__(1024) void ssim_finish(
    const float* __restrict__ partial, float* __restrict__ out)
{
    __shared__ float wred[16];
    const int t = threadIdx.x;
    float s = 0.f;
    #pragma unroll
    for (int i = 0; i < NPART / 1024; ++i)
        s += partial[t + i * 1024];
    #pragma unroll
    for (int off = 32; off > 0; off >>= 1)
        s += __shfl_down(s, off, 64);
    if ((t & 63) == 0) wred[t >> 6] = s;
    __syncthreads();
    if (t == 0) {
        float acc = 0.f;
        #pragma unroll
        for (int i = 0; i < 16; ++i) acc += wred[i];
        out[0] = 1.f - acc * (1.f / (float)((long long)NCH * IMG * IMG));
    }
}

extern "C" void kernel_launch(void* const* d_in, const int* in_sizes, int n_in,
                              void* d_out, int out_size, void* d_ws, size_t ws_size,
                              hipStream_t stream)
{
    const float* pred = (const float*)d_in[0];
    const float* tgt  = (const float*)d_in[1];
    float* out     = (float*)d_out;
    float* partial = (float*)d_ws;    // NPART floats = 96 KB

    ssim_tile_kernel<<<NBLK, 256, 0, stream>>>(pred, tgt, partial);
    ssim_finish<<<1, 1024, 0, stream>>>(partial, out);
}

// Round 16
// 128.140 us; speedup vs baseline: 1.0649x; 1.0172x over previous
//
#include <hip/hip_runtime.h>

// SSIM loss via MFMA band-matrix convolutions (gfx950).
// R24: f16 reg-staged window, 5 blocks/CU -- tile FLAT ~40.8us vs R21.
//   Tile pinned at FETCH/2.3TB/s across SIX structures. The ~87.5us harness
//   re-poison (2x256MB fills) flushes L3 each iter => 92MB must come from HBM.
//   Two surviving theories for 2.3 of 6.3 TB/s:
//   (A) compiler sinks staging loads per-unit (VGPR=44) -> 32B in flight per
//       thread, ~8KB/block << 22.5KB/CU Little's-law need;
//   (B) DRAM pattern ceiling for 320-576B bursts at 2KB stride.
// R25 (this round, discriminating experiment): INLINE-ASM batched staging --
//   volatile asm global_load_dwordx4 CANNOT be sunk (the failure mode of
//   R11/R15/R22). 8 loads issued per thread (128B in flight), ONE
//   s_waitcnt vmcnt(0) + sched_barrier(0) (rule 18) before cvt+ds_write.
//   launch_bounds(256,4) for +32 payload VGPRs.
//   If (A): tile ~27-31us, hbm ~3.4TB/s. If flat ~40us: (B) => roofline.

namespace {
constexpr int IMG   = 512;
constexpr int NCH   = 48;                  // 16 * 3
constexpr int TW    = 64;                  // tile cols
constexpr int TH    = 32;                  // tile rows
constexpr int WR    = 44;                  // staged window rows (ty-5..ty+38)
constexpr int WC    = 80;                  // staged window cols (tx-8..tx+71)
constexpr int SLOTS = WC / 8;              // 10 16B-f16-slots per row (8 cols)
constexpr int NU    = 2 * WR * SLOTS;      // 880 staging units
constexpr int TPX   = IMG / TW;            // 8
constexpr int TPY   = IMG / TH;            // 16
constexpr int NBLK  = TPX * TPY * NCH;     // 6144
constexpr int NPART = NBLK * 4;            // 24576 (one f32 per wave)
constexpr int RS    = 56;                  // scratch p-stride (f16): 112B rows,
                                           // 28nr mod 32 -> 8 bank-starts
constexpr float Wf[11] = {
    0.00102838f, 0.00759876f, 0.03600077f, 0.10936069f, 0.21300554f,
    0.26601172f,
    0.21300554f, 0.10936069f, 0.03600077f, 0.00759876f, 0.00102838f };

constexpr float band_wc(int d) {           // W[d] for d in [0,11), else 0
    return (d >= 0 && d < 11) ? Wf[d] : 0.f;
}

// constexpr f32 -> f16 bits, round-to-nearest-even (matches runtime cast).
constexpr unsigned short f2h(float f) {
    if (f == 0.f) return 0;
    unsigned u = __builtin_bit_cast(unsigned, f);
    int  he = int((u >> 23) & 0xff) - 127 + 15;
    unsigned hm   = (u & 0x7fffff) >> 13;
    unsigned rest = u & 0x1fff;
    if (rest > 0x1000 || (rest == 0x1000 && (hm & 1))) ++hm;
    return (unsigned short)((unsigned(he) << 10) + hm);
}

struct Tabs { unsigned short a[64][8]; unsigned short b[64][8]; };
constexpr Tabs build_tabs() {
    Tabs t{};
    for (int lane = 0; lane < 64; ++lane) {
        const int nr = lane & 15, quad = lane >> 4;
        for (int jj = 0; jj < 8; ++jj) {
            const int k = quad * 8 + jj;
            t.a[lane][jj] = f2h(band_wc(k - nr));       // V-pass A: W[k-m]
            t.b[lane][jj] = f2h(band_wc(k - nr - 3));   // H-pass B: W[k-n-3]
        }
    }
    return t;
}
}

__device__ __constant__ __align__(16) Tabs g_tabs = build_tabs();

typedef _Float16 half8 __attribute__((ext_vector_type(8)));
typedef _Float16 half4v __attribute__((ext_vector_type(4)));
typedef _Float16 h2 __attribute__((ext_vector_type(2)));
typedef float float4v __attribute__((ext_vector_type(4)));
typedef float float2v __attribute__((ext_vector_type(2)));

__device__ inline h2 pk(float a, float b) {
    auto v = __builtin_amdgcn_cvt_pkrtz(a, b);
    h2 r;
    __builtin_memcpy(&r, &v, sizeof(r));
    return r;
}

union H8 { half8 v; h2 p[4]; };

__global__ __launch_bounds__(256, 4) void ssim_tile_kernel(
    const float* __restrict__ pred, const float* __restrict__ tgt,
    float* __restrict__ partial)
{
    // f16 window, rotation-swizzled 16B slots:
    //   wf[tens][row][pos] holds logical slot (pos - row&7) mod 10
    __shared__ __align__(16) _Float16 wf[2][WR][SLOTS * 8];  // 14080 B
    // wave-private transpose scratch [wave][pingpong][x][p]
    __shared__ __align__(16) _Float16 sc[4][2][16][RS];      // 14336 B

    const int t    = threadIdx.x;
    const int w    = t >> 6;
    const int lane = t & 63;
    const int nr   = lane & 15;
    const int quad = lane >> 4;

    const int bid  = blockIdx.x;
    const int img  = bid >> 7;             // 128 tiles per plane (8 x 16)
    const int tile = bid & 127;
    const int tx   = (tile & 7) * TW;
    const int ty   = (tile >> 3) * TH;

    const float* __restrict__ p = pred + (size_t)img * (IMG * IMG);
    const float* __restrict__ q = tgt  + (size_t)img * (IMG * IMG);

    // ===== P1: stage window as f16, ASM-BATCHED loads =====
    // unit u: tens = u>=440; v = u-440t; row = v/10; pos = v%10;
    //   stored slot sl = (pos - row&7) mod 10; cols tx-8+8sl..+7
    {
        const float* srcs[4];
        int rowk[4], posk[4], tenk[4];
        bool valid[4];
        #pragma unroll
        for (int k = 0; k < 4; ++k) {
            int u = t + k * 256;
            valid[k] = (u < NU);
            if (!valid[k]) u = NU - 1;     // safe duplicate (clamped addrs)
            const int tens = (u >= NU / 2) ? 1 : 0;
            const int v    = u - tens * (NU / 2);
            const int row  = v / SLOTS;
            const int pos  = v - row * SLOTS;
            int sl = pos - (row & 7);
            if (sl < 0) sl += SLOTS;
            const int gy = min(max(ty - 5 + row, 0), IMG - 1);
            const int gx = min(max(tx - 8 + 8 * sl, 0), IMG - 8);
            srcs[k] = (tens ? q : p) + gy * IMG + gx;
            rowk[k] = row; posk[k] = pos; tenk[k] = tens;
        }
        float4 va[4], vb[4];
        #pragma unroll
        for (int k = 0; k < 4; ++k) {      // volatile asm: cannot be sunk
            asm volatile("global_load_dwordx4 %0, %1, off"
                         : "=&v"(va[k]) : "v"(srcs[k]) : "memory");
            asm volatile("global_load_dwordx4 %0, %1, off offset:16"
                         : "=&v"(vb[k]) : "v"(srcs[k]) : "memory");
        }
        asm volatile("s_waitcnt vmcnt(0)" ::: "memory");
        __builtin_amdgcn_sched_barrier(0); // rule 18: pin uses after waitcnt
        #pragma unroll
        for (int k = 0; k < 4; ++k) {
            if (valid[k]) {
                H8 h;
                h.p[0] = pk(va[k].x, va[k].y); h.p[1] = pk(va[k].z, va[k].w);
                h.p[2] = pk(vb[k].x, vb[k].y); h.p[3] = pk(vb[k].z, vb[k].w);
                *(half8*)&wf[tenk[k]][rowk[k]][posk[k] * 8] = h.v;
            }
        }
    }
    __syncthreads();

    // ---- band fragments from the compile-time table ----
    const half8 Aband = *(const half8*)(g_tabs.a[lane]);
    const half8 Bband = *(const half8*)(g_tabs.b[lane]);
    const float4v zf = {0.f, 0.f, 0.f, 0.f};
    const half8 z8 = {};

    constexpr float C1 = 1e-4f, C2 = 9e-4f;
    const float2v C1v = {C1, C1};
    const float2v C2v = {C2, C2};
    const float2v K12 = {C1 + C2, C1 + C2};
    float2v lsum2 = {0.f, 0.f};

    // ===== P2: each wave owns chunk c = w (16 output cols) =====
    {
        const int c = w;
        // frag col base tx+16c-8+8quad; zero when outside [0,512)
        const bool okc_ = ((unsigned)(tx + 16 * c - 8 + 8 * quad)
                           <= (unsigned)(IMG - 8));

        // ---- read 6 A-frags (3 stripes x {x,y}): ONE b128 each ----
        half8 fx[3], fy[3];
        #pragma unroll
        for (int s = 0; s < 3; ++s) {
            const int row  = 16 * s + nr;
            const int rowr = min(row, WR - 1);
            const bool ok  = okc_ && (row < WR) &&
                             ((unsigned)(ty - 5 + row) < (unsigned)IMG);
            const int sl = 2 * c + quad;           // logical 8-col slot
            int pos = sl + (rowr & 7);
            if (pos >= SLOTS) pos -= SLOTS;
            half8 ax = *(const half8*)&wf[0][rowr][pos * 8];
            half8 ay = *(const half8*)&wf[1][rowr][pos * 8];
            if (!ok) { ax = z8; ay = z8; }
            fx[s] = ax;
            fy[s] = ay;
        }

        // ---- H-MFMA -> transposed scratch -> V-MFMA (2-slot ping-pong) ----
        auto hw = [&](int slot, int s, float4v d) {
            h2 lo = pk(d[0], d[1]);
            h2 hi = pk(d[2], d[3]);
            half4v hh = {lo[0], lo[1], hi[0], hi[1]};
            *(half4v*)&sc[w][slot][nr][16 * s + 4 * quad] = hh;   // b64
        };
        auto rdv = [&](int slot, int pb) -> half8 {
            return *(const half8*)&sc[w][slot][nr][pb + 8 * quad]; // b128
        };
        #define HMA(a) __builtin_amdgcn_mfma_f32_16x16x32_f16((a), Bband, zf, 0, 0, 0)
        #define VMA(b) __builtin_amdgcn_mfma_f32_16x16x32_f16(Aband, (b), zf, 0, 0, 0)

        float4v a0[5], a1[5];   // V accumulators: out rows ty+.., ty+16+..
        // pass 1: x, y
        #pragma unroll
        for (int s = 0; s < 3; ++s) { hw(0, s, HMA(fx[s])); hw(1, s, HMA(fy[s])); }
        a0[0] = VMA(rdv(0, 0));  a1[0] = VMA(rdv(0, 16));
        a0[1] = VMA(rdv(1, 0));  a1[1] = VMA(rdv(1, 16));
        // pass 2: x*x, y*y (same-wave DS order: reads above precede writes)
        #pragma unroll
        for (int s = 0; s < 3; ++s) { hw(0, s, HMA(fx[s] * fx[s])); hw(1, s, HMA(fy[s] * fy[s])); }
        a0[2] = VMA(rdv(0, 0));  a1[2] = VMA(rdv(0, 16));
        a0[3] = VMA(rdv(1, 0));  a1[3] = VMA(rdv(1, 16));
        // pass 3: x*y
        #pragma unroll
        for (int s = 0; s < 3; ++s) { hw(0, s, HMA(fx[s] * fy[s])); }
        a0[4] = VMA(rdv(0, 0));  a1[4] = VMA(rdv(0, 16));
        #undef HMA
        #undef VMA

        // ---- packed-f32 SSIM epilogue for both 16-row halves ----
        #pragma unroll
        for (int v = 0; v < 2; ++v) {
            const float4v* A = v ? a1 : a0;
            #pragma unroll
            for (int h = 0; h < 2; ++h) {
                float2v mx  = {A[0][2*h], A[0][2*h+1]};
                float2v my  = {A[1][2*h], A[1][2*h+1]};
                float2v ex2 = {A[2][2*h], A[2][2*h+1]};
                float2v ey2 = {A[3][2*h], A[3][2*h+1]};
                float2v exy = {A[4][2*h], A[4][2*h+1]};
                float2v P  = mx * my;
                float2v U  = mx * mx + my * my + C1v;
                float2v n1 = 2.f * P + C1v;
                float2v n2 = 2.f * (exy - P) + C2v;
                float2v num = n1 * n2;
                float2v e1 = (ex2 + ey2) - U + K12;
                float2v den = U * e1;
                float2v r = {__builtin_amdgcn_rcpf(den.x),
                             __builtin_amdgcn_rcpf(den.y)};
                lsum2 += num * r;
            }
        }
    }

    float lsum = lsum2.x + lsum2.y;
    #pragma unroll
    for (int off = 32; off > 0; off >>= 1)
        lsum += __shfl_down(lsum, off, 64);
    if (lane == 0) partial[(bid << 2) + w] = lsum;
}

// Single-block finish: 1024 threads x 24 loads, deterministic tree reduce.
__global__ __launch_bounds__(1024) void ssim_finish(
    const float* __restrict__ partial, float* __restrict__ out)
{
    __shared__ float wred[16];
    const int t = threadIdx.x;
    float s = 0.f;
    #pragma unroll
    for (int i = 0; i < NPART / 1024; ++i)
        s += partial[t + i * 1024];
    #pragma unroll
    for (int off = 32; off > 0; off >>= 1)
        s += __shfl_down(s, off, 64);
    if ((t & 63) == 0) wred[t >> 6] = s;
    __syncthreads();
    if (t == 0) {
        float acc = 0.f;
        #pragma unroll
        for (int i = 0; i < 16; ++i) acc += wred[i];
        out[0] = 1.f - acc * (1.f / (float)((long long)NCH * IMG * IMG));
    }
}

extern "C" void kernel_launch(void* const* d_in, const int* in_sizes, int n_in,
                              void* d_out, int out_size, void* d_ws, size_t ws_size,
                              hipStream_t stream)
{
    const float* pred = (const float*)d_in[0];
    const float* tgt  = (const float*)d_in[1];
    float* out     = (float*)d_out;
    float* partial = (float*)d_ws;    // NPART floats = 96 KB

    ssim_tile_kernel<<<NBLK, 256, 0, stream>>>(pred, tgt, partial);
    ssim_finish<<<1, 1024, 0, stream>>>(partial, out);
}